// Round 17
// baseline (106.088 us; speedup 1.0000x reference)
//
#include <hip/hip_runtime.h>
#include <stdint.h>

#define B_ 128
#define F_ 128
#define T_ 512
#define TS 64
#define DIAG_N 1024   // padded diagonal count (1023 used, row 1023 junk-but-allocated)

// Large finite sentinel instead of INF: survives fast-math, never overflows.
#define BIGV 1e30f

typedef __attribute__((ext_vector_type(8))) short     bf16x8;
typedef __attribute__((ext_vector_type(4))) float     f32x4;

static __device__ __forceinline__ unsigned short f32_to_bf16(float f) {
    union { float f; uint32_t u; } v; v.f = f;
    const uint32_t u = v.u + 0x7fffu + ((v.u >> 16) & 1u);   // RNE
    return (unsigned short)(u >> 16);
}

// DPP wave shifts — single-VALU whole-wave lane shifts.
static __device__ __forceinline__ float wave_shr1(float src, float fill) {
    const int r = __builtin_amdgcn_update_dpp(
        __builtin_bit_cast(int, fill), __builtin_bit_cast(int, src),
        0x138, 0xf, 0xf, false);
    return __builtin_bit_cast(float, r);
}
static __device__ __forceinline__ float wave_shl1(float src, float fill) {
    const int r = __builtin_amdgcn_update_dpp(
        __builtin_bit_cast(int, fill), __builtin_bit_cast(int, src),
        0x130, 0xf, 0xf, false);
    return __builtin_bit_cast(float, r);
}

// n = f16(lo/hi half of h) * 1.0 + m — one v_fma_mix_f32 (R15-proven).
#define FMIX_LO(dst, h, m)                                                  \
    asm("v_fma_mix_f32 %0, %1, 1.0, %2 op_sel:[0,0,0] op_sel_hi:[1,0,0]"    \
        : "=v"(dst) : "v"(h), "v"(m))
#define FMIX_HI(dst, h, m)                                                  \
    asm("v_fma_mix_f32 %0, %1, 1.0, %2 op_sel:[1,0,0] op_sel_hi:[1,0,0]"    \
        : "=v"(dst) : "v"(h), "v"(m))

// ---------------------------------------------------------------------------
// Kernel 0: prep (unchanged — passing since R4).
// ---------------------------------------------------------------------------
__global__ __launch_bounds__(256) void dtw_prep_kernel(
    const float* __restrict__ x, const float* __restrict__ y,
    unsigned short* __restrict__ xt, unsigned short* __restrict__ yt,
    float* __restrict__ nx, float* __restrict__ ny)
{
    const int tch = blockIdx.x;
    const int b   = blockIdx.y;
    const int z   = blockIdx.z;
    const int tid = threadIdx.x;
    const int t0  = tch * 64;

    const float* src      = (z == 0 ? x : y) + (size_t)b * F_ * T_;
    unsigned short* dst   = (z == 0 ? xt : yt) + (size_t)b * T_ * F_;
    float* nd             = (z == 0 ? nx : ny) + (size_t)b * T_;

    __shared__ float S[F_][65];

    const int fr = tid >> 4;
    const int q  = (tid & 15) * 4;
#pragma unroll
    for (int p = 0; p < 8; ++p) {
        const int f = p * 16 + fr;
        const float4 v = *(const float4*)(src + (size_t)f * T_ + t0 + q);
        S[f][q] = v.x; S[f][q + 1] = v.y; S[f][q + 2] = v.z; S[f][q + 3] = v.w;
    }
    __syncthreads();

    if (tid < 64) {
        float s = 0.f;
#pragma unroll
        for (int f = 0; f < F_; ++f) { const float v = S[f][tid]; s = fmaf(v, v, s); }
        nd[t0 + tid] = s;
    }

    const int tl = tid >> 2;
    const int fb = (tid & 3) * 32;
    uint32_t pk[16];
#pragma unroll
    for (int e = 0; e < 16; ++e) {
        const uint32_t lo = f32_to_bf16(S[fb + 2 * e][tl]);
        const uint32_t hi = f32_to_bf16(S[fb + 2 * e + 1][tl]);
        pk[e] = lo | (hi << 16);
    }
    uint32_t* o = (uint32_t*)(dst + (size_t)(t0 + tl) * F_ + fb);
#pragma unroll
    for (int e = 0; e < 16; e += 4)
        *(uint4*)(o + e) = make_uint4(pk[e], pk[e + 1], pk[e + 2], pk[e + 3]);
}

// ---------------------------------------------------------------------------
// Kernel 1: cost (byte-identical to passing R13/R15 hybrid).
// ---------------------------------------------------------------------------
__global__ __launch_bounds__(256) void dtw_cost_kernel(
    const unsigned short* __restrict__ xt, const unsigned short* __restrict__ yt,
    const float* __restrict__ nx, const float* __restrict__ ny,
    unsigned short* __restrict__ costD, int b0)
{
    const int tj  = blockIdx.x;
    const int ti  = blockIdx.y;
    const int bl  = blockIdx.z;
    const int b   = b0 + bl;
    const int tid = threadIdx.x;
    const int gi0 = ti * TS;
    const int gj0 = tj * TS;

    const int w    = tid >> 6;
    const int lane = tid & 63;
    const int l15  = lane & 15;
    const int hi   = lane >> 4;

    __shared__ __align__(16) char smem[16384];
    unsigned short* Ys = (unsigned short*)smem;

    {
        const int l16 = tid & 15;
#pragma unroll
        for (int p = 0; p < 4; ++p) {
            const int row = p * 16 + (tid >> 4);
            const uint4 vy = *(const uint4*)(yt + ((size_t)b * T_ + gj0 + row) * F_ + l16 * 8);
            const int byt = (row * 256 + l16 * 16) ^ ((row & 7) << 4);
            *(uint4*)((char*)Ys + byt) = vy;
        }
    }

    const unsigned short* xb = xt + ((size_t)b * T_ + gi0 + 16 * w + l15) * F_ + hi * 8;
    const bf16x8 A0 = *(const bf16x8*)(xb);
    const bf16x8 A1 = *(const bf16x8*)(xb + 32);
    const bf16x8 A2 = *(const bf16x8*)(xb + 64);
    const bf16x8 A3 = *(const bf16x8*)(xb + 96);

    const float4 x2r = *(const float4*)(nx + (size_t)b * T_ + gi0 + 16 * w + 4 * hi);
    float y2c[4];
#pragma unroll
    for (int nt = 0; nt < 4; ++nt)
        y2c[nt] = ny[(size_t)b * T_ + gj0 + nt * 16 + l15];
    const float x2v[4] = {x2r.x, x2r.y, x2r.z, x2r.w};

    __syncthreads();

    f32x4 acc[4] = {};
#pragma unroll
    for (int kb = 0; kb < 4; ++kb) {
        const int koff = kb * 64 + hi * 16;
        const bf16x8 a = (kb == 0) ? A0 : (kb == 1) ? A1 : (kb == 2) ? A2 : A3;
#pragma unroll
        for (int nt = 0; nt < 4; ++nt) {
            const int col = nt * 16 + l15;
            const bf16x8 bb = *(const bf16x8*)((const char*)Ys +
                               ((col * 256 + koff) ^ ((col & 7) << 4)));
            acc[nt] = __builtin_amdgcn_mfma_f32_16x16x32_bf16(a, bb, acc[nt], 0, 0, 0);
        }
    }

    __syncthreads();                        // all MFMA LDS reads complete
    unsigned short* Ts = (unsigned short*)smem;
#pragma unroll
    for (int nt = 0; nt < 4; ++nt) {
        const int col = nt * 16 + l15;
#pragma unroll
        for (int r = 0; r < 4; ++r) {
            const int row = 16 * w + hi * 4 + r;
            const float c = sqrtf(fmaxf(x2v[r] + y2c[nt] - 2.f * acc[nt][r], 0.f));
            const _Float16 hv = (_Float16)c;       // RNE
            Ts[row * 67 + col] = *(const unsigned short*)&hv;
        }
    }
    __syncthreads();

    unsigned short* outD = costD + (size_t)bl * (DIAG_N * (size_t)T_);
    const int tbase = gi0 + gj0;
#pragma unroll
    for (int q = 0; q < 16; ++q) {
        const int g = q * 4 + w;                    // 0..63
        const int d = (lane <= g) ? g : g + 64;     // g=63: all lanes -> 63
        outD[(size_t)(tbase + d) * T_ + gj0 + lane] = Ts[(d - lane) * 67 + lane];
    }
}

// ---------------------------------------------------------------------------
// Kernel 2: DIRECTION-SPLIT DTW DP with R15's PROVEN depth-3 schedule.
// One 64-thread block per (batch, direction): blocks [0,Bg) forward (diags
// 0..511), [Bg,2Bg) backward (diags 1022..512). 32 KB 4-slot ring, 24 loads
// outstanding, WAITV(16) steady (identical to R15's per-wave schedule — R16
// changed depth AND split together and regressed; this isolates the split).
// Rationale: every dp variant pins at ~7 B/cy fetched per CU (R7-R16), i.e.
// per-CU fetch-BW-bound. Splitting fwd/bwd onto different CUs halves
// bytes/CU -> dp should halve. Handoff via global f32 scratch; combine in
// kernel 3 (R16-proven).
// ---------------------------------------------------------------------------
__global__ __launch_bounds__(64, 1) void dtw_dp_dir(
    const unsigned short* __restrict__ costD, float* __restrict__ hand, int Bg)
{
    const int isB = (int)blockIdx.x >= Bg;
    const int bl  = isB ? (int)blockIdx.x - Bg : (int)blockIdx.x;
    const int L   = threadIdx.x;
    const unsigned short* gbase = costD + (size_t)bl * (DIAG_N * (size_t)T_) + 8 * L;

    __shared__ __align__(16) unsigned short ring[32][T_];   // 32 KB, 4 slots

    float va0 = BIGV, va1 = BIGV, va2 = BIGV, va3 = BIGV,
          va4 = BIGV, va5 = BIGV, va6 = BIGV, va7 = BIGV;
    float vb0 = BIGV, vb1 = BIGV, vb2 = BIGV, vb3 = BIGV,
          vb4 = BIGV, vb5 = BIGV, vb6 = BIGV, vb7 = BIGV;
    float s2c;
    uint4 ca0, ca1, ca2, ca3, ca4, ca5, ca6, ca7;
    uint4 cb0, cb1, cb2, cb3, cb4, cb5, cb6, cb7;

#define GLD(row, slotrow)                                                   \
    __builtin_amdgcn_global_load_lds(                                       \
        (const __attribute__((address_space(1))) void*)(gbase + (size_t)(row) * T_), \
        (__attribute__((address_space(3))) void*)(&ring[slotrow][0]), 16, 0, 0)

#define GLD8F(blk) do {                                                     \
    const int r0_ = (blk) * 8, s0_ = ((blk) & 3) * 8;                       \
    GLD(r0_ + 0, s0_ + 0); GLD(r0_ + 1, s0_ + 1);                           \
    GLD(r0_ + 2, s0_ + 2); GLD(r0_ + 3, s0_ + 3);                           \
    GLD(r0_ + 4, s0_ + 4); GLD(r0_ + 5, s0_ + 5);                           \
    GLD(r0_ + 6, s0_ + 6); GLD(r0_ + 7, s0_ + 7);                           \
} while (0)

#define GLD8B(blk) do {                                                     \
    const int v0_ = (blk) * 8, s0_ = ((blk) & 3) * 8;                       \
    GLD(1022 - (v0_ + 0), s0_ + 0); GLD(1022 - (v0_ + 1), s0_ + 1);         \
    GLD(1022 - (v0_ + 2), s0_ + 2); GLD(1022 - (v0_ + 3), s0_ + 3);         \
    GLD(1022 - (v0_ + 4), s0_ + 4); GLD(1022 - (v0_ + 5), s0_ + 5);         \
    GLD(1022 - (v0_ + 6), s0_ + 6); GLD(1022 - (v0_ + 7), s0_ + 7);         \
} while (0)

#define WAITV(n)                                                            \
    do { asm volatile("s_waitcnt vmcnt(" #n ")" ::: "memory");              \
         __builtin_amdgcn_sched_barrier(0); } while (0)

#define SB __builtin_amdgcn_sched_barrier(0)

#define RL8(BK, blk) do {                                                   \
    const unsigned short* rp_ = &ring[((blk) & 3) * 8][8 * L];              \
    BK##0 = *(const uint4*)(rp_ + 0 * T_);                                  \
    BK##1 = *(const uint4*)(rp_ + 1 * T_);                                  \
    BK##2 = *(const uint4*)(rp_ + 2 * T_);                                  \
    BK##3 = *(const uint4*)(rp_ + 3 * T_);                                  \
    BK##4 = *(const uint4*)(rp_ + 4 * T_);                                  \
    BK##5 = *(const uint4*)(rp_ + 5 * T_);                                  \
    BK##6 = *(const uint4*)(rp_ + 6 * T_);                                  \
    BK##7 = *(const uint4*)(rp_ + 7 * T_);                                  \
} while (0)

#define STEPF_A(Hv) do {                                                    \
    const float s1 = wave_shr1(va7, BIGV);                                  \
    float n0, n1, n2, n3, n4, n5, n6, n7;                                   \
    FMIX_LO(n0, Hv.x, fminf(fminf(va0, s1),  s2c));                         \
    FMIX_HI(n1, Hv.x, fminf(fminf(va1, va0), vb0));                         \
    FMIX_LO(n2, Hv.y, fminf(fminf(va2, va1), vb1));                         \
    FMIX_HI(n3, Hv.y, fminf(fminf(va3, va2), vb2));                         \
    FMIX_LO(n4, Hv.z, fminf(fminf(va4, va3), vb3));                         \
    FMIX_HI(n5, Hv.z, fminf(fminf(va5, va4), vb4));                         \
    FMIX_LO(n6, Hv.w, fminf(fminf(va6, va5), vb5));                         \
    FMIX_HI(n7, Hv.w, fminf(fminf(va7, va6), vb6));                         \
    s2c = s1;                                                               \
    vb0 = n0; vb1 = n1; vb2 = n2; vb3 = n3;                                 \
    vb4 = n4; vb5 = n5; vb6 = n6; vb7 = n7;                                 \
} while (0)

#define STEPF_B(Hv) do {                                                    \
    const float s1 = wave_shr1(vb7, BIGV);                                  \
    float n0, n1, n2, n3, n4, n5, n6, n7;                                   \
    FMIX_LO(n0, Hv.x, fminf(fminf(vb0, s1),  s2c));                         \
    FMIX_HI(n1, Hv.x, fminf(fminf(vb1, vb0), va0));                         \
    FMIX_LO(n2, Hv.y, fminf(fminf(vb2, vb1), va1));                         \
    FMIX_HI(n3, Hv.y, fminf(fminf(vb3, vb2), va2));                         \
    FMIX_LO(n4, Hv.z, fminf(fminf(vb4, vb3), va3));                         \
    FMIX_HI(n5, Hv.z, fminf(fminf(vb5, vb4), va4));                         \
    FMIX_LO(n6, Hv.w, fminf(fminf(vb6, vb5), va5));                         \
    FMIX_HI(n7, Hv.w, fminf(fminf(vb7, vb6), va6));                         \
    s2c = s1;                                                               \
    va0 = n0; va1 = n1; va2 = n2; va3 = n3;                                 \
    va4 = n4; va5 = n5; va6 = n6; va7 = n7;                                 \
} while (0)

#define STEPB_A(Hv) do {                                                    \
    const float s1 = wave_shl1(va0, BIGV);                                  \
    float n0, n1, n2, n3, n4, n5, n6, n7;                                   \
    FMIX_HI(n7, Hv.w, fminf(fminf(va7, s1),  s2c));                         \
    FMIX_LO(n6, Hv.w, fminf(fminf(va6, va7), vb7));                         \
    FMIX_HI(n5, Hv.z, fminf(fminf(va5, va6), vb6));                         \
    FMIX_LO(n4, Hv.z, fminf(fminf(va4, va5), vb5));                         \
    FMIX_HI(n3, Hv.y, fminf(fminf(va3, va4), vb4));                         \
    FMIX_LO(n2, Hv.y, fminf(fminf(va2, va3), vb3));                         \
    FMIX_HI(n1, Hv.x, fminf(fminf(va1, va2), vb2));                         \
    FMIX_LO(n0, Hv.x, fminf(fminf(va0, va1), vb1));                         \
    s2c = s1;                                                               \
    vb0 = n0; vb1 = n1; vb2 = n2; vb3 = n3;                                 \
    vb4 = n4; vb5 = n5; vb6 = n6; vb7 = n7;                                 \
} while (0)

#define STEPB_B(Hv) do {                                                    \
    const float s1 = wave_shl1(vb0, BIGV);                                  \
    float n0, n1, n2, n3, n4, n5, n6, n7;                                   \
    FMIX_HI(n7, Hv.w, fminf(fminf(vb7, s1),  s2c));                         \
    FMIX_LO(n6, Hv.w, fminf(fminf(vb6, vb7), va7));                         \
    FMIX_HI(n5, Hv.z, fminf(fminf(vb5, vb6), va6));                         \
    FMIX_LO(n4, Hv.z, fminf(fminf(vb4, vb5), va5));                         \
    FMIX_HI(n3, Hv.y, fminf(fminf(vb3, vb4), va4));                         \
    FMIX_LO(n2, Hv.y, fminf(fminf(vb2, vb3), va3));                         \
    FMIX_HI(n1, Hv.x, fminf(fminf(vb1, vb2), va2));                         \
    FMIX_LO(n0, Hv.x, fminf(fminf(vb0, vb1), va1));                         \
    s2c = s1;                                                               \
    va0 = n0; va1 = n1; va2 = n2; va3 = n3;                                 \
    va4 = n4; va5 = n5; va6 = n6; va7 = n7;                                 \
} while (0)

#define STEPF8(BK)                                                          \
    STEPF_A(BK##0); STEPF_B(BK##1); STEPF_A(BK##2); STEPF_B(BK##3);         \
    STEPF_A(BK##4); STEPF_B(BK##5); STEPF_A(BK##6); STEPF_B(BK##7)
#define STEPB8(BK)                                                          \
    STEPB_A(BK##0); STEPB_B(BK##1); STEPB_A(BK##2); STEPB_B(BK##3);         \
    STEPB_A(BK##4); STEPB_B(BK##5); STEPB_A(BK##6); STEPB_B(BK##7)

    float* hb = hand + (size_t)bl * 4 * T_;

    if (!isB) {
        // -------- forward: diags 0..511, R15 schedule (depth-3) --------
        s2c = (L == 0) ? 0.f : BIGV;       // seeds dp[-1][-1] = 0
#pragma unroll
        for (int r = 0; r < 32; ++r) GLD(r, r);
        WAITV(24); RL8(ca, 0); SB;
        int k = 0;
#pragma unroll 1
        for (int it = 0; it < 30; ++it) {  // blocks 0..59
            WAITV(16); RL8(cb, k + 1); SB; STEPF8(ca); SB; GLD8F(k + 4); SB;
            WAITV(16); RL8(ca, k + 2); SB; STEPF8(cb); SB; GLD8F(k + 5); SB;
            k += 2;
        }
        // k = 60; in flight: blocks 61,62,63
        WAITV(16); RL8(cb, 61); SB; STEPF8(ca); SB;     // block 60
        WAITV(8);  RL8(ca, 62); SB; STEPF8(cb); SB;     // block 61
        WAITV(0);  RL8(cb, 63); SB; STEPF8(ca); SB;     // block 62
        STEPF8(cb);                                     // block 63 -> tick 511
        // va = F511, vb = F510
        *(float4*)(hb + 0 * T_ + 8 * L)     = make_float4(va0, va1, va2, va3);
        *(float4*)(hb + 0 * T_ + 8 * L + 4) = make_float4(va4, va5, va6, va7);
        *(float4*)(hb + 1 * T_ + 8 * L)     = make_float4(vb0, vb1, vb2, vb3);
        *(float4*)(hb + 1 * T_ + 8 * L + 4) = make_float4(vb4, vb5, vb6, vb7);
    } else {
        // -------- backward: diags 1022..512, R15 schedule --------
        s2c = (L == 63) ? 0.f : BIGV;      // seeds B beyond (511,511)
#pragma unroll
        for (int r = 0; r < 32; ++r) GLD(1022 - r, r);
        WAITV(24); RL8(ca, 0); SB;
        int k = 0;
#pragma unroll 1
        for (int it = 0; it < 30; ++it) {  // blocks 0..59
            WAITV(16); RL8(cb, k + 1); SB; STEPB8(ca); SB; GLD8B(k + 4); SB;
            WAITV(16); RL8(ca, k + 2); SB; STEPB8(cb); SB; GLD8B(k + 5); SB;
            k += 2;
        }
        WAITV(16); RL8(cb, 61); SB; STEPB8(ca); SB;     // block 60
        WAITV(8);  RL8(ca, 62); SB; STEPB8(cb); SB;     // block 61
        WAITV(0);  RL8(cb, 63); SB; STEPB8(ca); SB;     // block 62
        // block 63 tail: 7 steps (rows 518..512); cb7 (row 511) never stepped
        STEPB_A(cb0); STEPB_B(cb1); STEPB_A(cb2); STEPB_B(cb3);
        STEPB_A(cb4); STEPB_B(cb5); STEPB_A(cb6);       // vb=B512, va=B513
        *(float4*)(hb + 2 * T_ + 8 * L)     = make_float4(vb0, vb1, vb2, vb3);
        *(float4*)(hb + 2 * T_ + 8 * L + 4) = make_float4(vb4, vb5, vb6, vb7);
        *(float4*)(hb + 3 * T_ + 8 * L)     = make_float4(va0, va1, va2, va3);
        *(float4*)(hb + 3 * T_ + 8 * L + 4) = make_float4(va4, va5, va6, va7);
    }

#undef GLD
#undef GLD8F
#undef GLD8B
#undef WAITV
#undef SB
#undef RL8
#undef STEPF_A
#undef STEPF_B
#undef STEPB_A
#undef STEPB_B
#undef STEPF8
#undef STEPB8
}

// ---------------------------------------------------------------------------
// Kernel 3: combine fwd/bwd at the diag-511/512 cut (R16-proven).
// ---------------------------------------------------------------------------
__global__ __launch_bounds__(64) void dtw_combine(
    const float* __restrict__ hand, float* __restrict__ out, int b0)
{
    const int bl = blockIdx.x;
    const int L  = threadIdx.x;
    const float* hb = hand + (size_t)bl * 4 * T_;

    const float4 f0 = *(const float4*)(hb + 0 * T_ + 8 * L);
    const float4 f1 = *(const float4*)(hb + 0 * T_ + 8 * L + 4);
    const float4 g0 = *(const float4*)(hb + 1 * T_ + 8 * L);
    const float4 g1 = *(const float4*)(hb + 1 * T_ + 8 * L + 4);
    const float4 p0 = *(const float4*)(hb + 2 * T_ + 8 * L);
    const float4 p1 = *(const float4*)(hb + 2 * T_ + 8 * L + 4);
    const float4 q0 = *(const float4*)(hb + 3 * T_ + 8 * L);
    const float4 q1 = *(const float4*)(hb + 3 * T_ + 8 * L + 4);

    const float F511[8] = {f0.x, f0.y, f0.z, f0.w, f1.x, f1.y, f1.z, f1.w};
    const float F510[8] = {g0.x, g0.y, g0.z, g0.w, g1.x, g1.y, g1.z, g1.w};
    const float b2[8]   = {p0.x, p0.y, p0.z, p0.w, p1.x, p1.y, p1.z, p1.w};
    const float b3[8]   = {q0.x, q0.y, q0.z, q0.w, q1.x, q1.y, q1.z, q1.w};

    float b2s[8], b3s[8];
#pragma unroll
    for (int kk = 0; kk < 7; ++kk) { b2s[kk] = b2[kk + 1]; b3s[kk] = b3[kk + 1]; }
    b2s[7] = wave_shl1(b2[0], BIGV);   // j+1 across lane boundary; j=511 -> BIGV
    b3s[7] = wave_shl1(b3[0], BIGV);

    float m = BIGV;
#pragma unroll
    for (int kk = 0; kk < 8; ++kk) {
        const float t1 = F511[kk] + fminf(fminf(b2[kk], b2s[kk]), b3s[kk]);
        const float t2 = F510[kk] + b2s[kk];
        m = fminf(m, fminf(t1, t2));
    }
#pragma unroll
    for (int off = 1; off < 64; off <<= 1)
        m = fminf(m, __shfl_xor(m, off));
    if (L == 0) out[b0 + bl] = m;
}

// ---------------------------------------------------------------------------
extern "C" void kernel_launch(void* const* d_in, const int* in_sizes, int n_in,
                              void* d_out, int out_size, void* d_ws, size_t ws_size,
                              hipStream_t stream)
{
    const float* x = (const float*)d_in[0];
    const float* y = (const float*)d_in[1];
    float* out = (float*)d_out;

    unsigned short* xt = (unsigned short*)d_ws;
    unsigned short* yt = xt + (size_t)B_ * T_ * F_;
    float* nx = (float*)(yt + (size_t)B_ * T_ * F_);
    float* ny = nx + (size_t)B_ * T_;
    unsigned short* costD = (unsigned short*)(ny + (size_t)B_ * T_);
    const size_t head = (size_t)((char*)costD - (char*)d_ws);

    // per-batch: diag cost (1 MiB f16) + handoff (4 rows x 512 f32 = 8 KiB)
    const size_t perb = (size_t)DIAG_N * T_ * sizeof(unsigned short)
                      + (size_t)4 * T_ * sizeof(float);
    int Bg = 8;
    for (int g = 128; g >= 8; g >>= 1)
        if (ws_size >= head + perb * (size_t)g) { Bg = g; break; }

    float* hand = (float*)(costD + (size_t)Bg * DIAG_N * T_);

    hipLaunchKernelGGL(dtw_prep_kernel, dim3(T_ / 64, B_, 2), dim3(256), 0, stream,
                       x, y, xt, yt, nx, ny);

    for (int b0 = 0; b0 < B_; b0 += Bg) {
        dim3 gc(T_ / TS, T_ / TS, Bg);
        hipLaunchKernelGGL(dtw_cost_kernel, gc, dim3(256), 0, stream,
                           xt, yt, nx, ny, costD, b0);
        hipLaunchKernelGGL(dtw_dp_dir, dim3(2 * Bg), dim3(64), 0, stream,
                           costD, hand, Bg);
        hipLaunchKernelGGL(dtw_combine, dim3(Bg), dim3(64), 0, stream,
                           hand, out, b0);
    }
}

// Round 18
// 97.004 us; speedup vs baseline: 1.0936x; 1.0936x over previous
//
#include <hip/hip_runtime.h>
#include <stdint.h>

#define B_ 128
#define F_ 128
#define T_ 512
#define TS 64
#define DIAG_N 1024   // padded diagonal count (1023 used)

// Large finite sentinel instead of INF: survives fast-math, never overflows.
#define BIGV 1e30f

typedef __attribute__((ext_vector_type(8))) short     bf16x8;
typedef __attribute__((ext_vector_type(4))) float     f32x4;
typedef __attribute__((ext_vector_type(2))) float     f32x2;

static __device__ __forceinline__ unsigned short f32_to_bf16(float f) {
    union { float f; uint32_t u; } v; v.f = f;
    const uint32_t u = v.u + 0x7fffu + ((v.u >> 16) & 1u);   // RNE
    return (unsigned short)(u >> 16);
}

// DPP wave shifts — single-VALU whole-wave lane shifts.
static __device__ __forceinline__ float wave_shr1(float src, float fill) {
    const int r = __builtin_amdgcn_update_dpp(
        __builtin_bit_cast(int, fill), __builtin_bit_cast(int, src),
        0x138, 0xf, 0xf, false);
    return __builtin_bit_cast(float, r);
}
static __device__ __forceinline__ float wave_shl1(float src, float fill) {
    const int r = __builtin_amdgcn_update_dpp(
        __builtin_bit_cast(int, fill), __builtin_bit_cast(int, src),
        0x130, 0xf, 0xf, false);
    return __builtin_bit_cast(float, r);
}

// ---------------------------------------------------------------------------
// Kernel 0: prep (unchanged — passing since R4).
// ---------------------------------------------------------------------------
__global__ __launch_bounds__(256) void dtw_prep_kernel(
    const float* __restrict__ x, const float* __restrict__ y,
    unsigned short* __restrict__ xt, unsigned short* __restrict__ yt,
    float* __restrict__ nx, float* __restrict__ ny)
{
    const int tch = blockIdx.x;
    const int b   = blockIdx.y;
    const int z   = blockIdx.z;
    const int tid = threadIdx.x;
    const int t0  = tch * 64;

    const float* src      = (z == 0 ? x : y) + (size_t)b * F_ * T_;
    unsigned short* dst   = (z == 0 ? xt : yt) + (size_t)b * T_ * F_;
    float* nd             = (z == 0 ? nx : ny) + (size_t)b * T_;

    __shared__ float S[F_][65];

    const int fr = tid >> 4;
    const int q  = (tid & 15) * 4;
#pragma unroll
    for (int p = 0; p < 8; ++p) {
        const int f = p * 16 + fr;
        const float4 v = *(const float4*)(src + (size_t)f * T_ + t0 + q);
        S[f][q] = v.x; S[f][q + 1] = v.y; S[f][q + 2] = v.z; S[f][q + 3] = v.w;
    }
    __syncthreads();

    if (tid < 64) {
        float s = 0.f;
#pragma unroll
        for (int f = 0; f < F_; ++f) { const float v = S[f][tid]; s = fmaf(v, v, s); }
        nd[t0 + tid] = s;
    }

    const int tl = tid >> 2;
    const int fb = (tid & 3) * 32;
    uint32_t pk[16];
#pragma unroll
    for (int e = 0; e < 16; ++e) {
        const uint32_t lo = f32_to_bf16(S[fb + 2 * e][tl]);
        const uint32_t hi = f32_to_bf16(S[fb + 2 * e + 1][tl]);
        pk[e] = lo | (hi << 16);
    }
    uint32_t* o = (uint32_t*)(dst + (size_t)(t0 + tl) * F_ + fb);
#pragma unroll
    for (int e = 0; e < 16; e += 4)
        *(uint4*)(o + e) = make_uint4(pk[e], pk[e + 1], pk[e + 2], pk[e + 3]);
}

// ---------------------------------------------------------------------------
// Kernel 1: cost (R13/R15-proven hybrid) with FP8-E4M3 diagonal output.
// Ts transpose buffer stays f16 (proven); the scatter converts f16->f32->fp8
// via v_cvt_pk_fp8_f32 and stores 1 byte/lane (64 contiguous B per wave-op).
// fp8 storage halves costD to 0.5 MiB/batch -> all 128 batches fit ws ->
// ONE dp dispatch (dp serial wall paid once, not twice).
// ---------------------------------------------------------------------------
__global__ __launch_bounds__(256) void dtw_cost_kernel(
    const unsigned short* __restrict__ xt, const unsigned short* __restrict__ yt,
    const float* __restrict__ nx, const float* __restrict__ ny,
    unsigned char* __restrict__ costD, int b0)
{
    const int tj  = blockIdx.x;
    const int ti  = blockIdx.y;
    const int bl  = blockIdx.z;
    const int b   = b0 + bl;
    const int tid = threadIdx.x;
    const int gi0 = ti * TS;
    const int gj0 = tj * TS;

    const int w    = tid >> 6;
    const int lane = tid & 63;
    const int l15  = lane & 15;
    const int hi   = lane >> 4;

    __shared__ __align__(16) char smem[16384];
    unsigned short* Ys = (unsigned short*)smem;

    {
        const int l16 = tid & 15;
#pragma unroll
        for (int p = 0; p < 4; ++p) {
            const int row = p * 16 + (tid >> 4);
            const uint4 vy = *(const uint4*)(yt + ((size_t)b * T_ + gj0 + row) * F_ + l16 * 8);
            const int byt = (row * 256 + l16 * 16) ^ ((row & 7) << 4);
            *(uint4*)((char*)Ys + byt) = vy;
        }
    }

    const unsigned short* xb = xt + ((size_t)b * T_ + gi0 + 16 * w + l15) * F_ + hi * 8;
    const bf16x8 A0 = *(const bf16x8*)(xb);
    const bf16x8 A1 = *(const bf16x8*)(xb + 32);
    const bf16x8 A2 = *(const bf16x8*)(xb + 64);
    const bf16x8 A3 = *(const bf16x8*)(xb + 96);

    const float4 x2r = *(const float4*)(nx + (size_t)b * T_ + gi0 + 16 * w + 4 * hi);
    float y2c[4];
#pragma unroll
    for (int nt = 0; nt < 4; ++nt)
        y2c[nt] = ny[(size_t)b * T_ + gj0 + nt * 16 + l15];
    const float x2v[4] = {x2r.x, x2r.y, x2r.z, x2r.w};

    __syncthreads();

    f32x4 acc[4] = {};
#pragma unroll
    for (int kb = 0; kb < 4; ++kb) {
        const int koff = kb * 64 + hi * 16;
        const bf16x8 a = (kb == 0) ? A0 : (kb == 1) ? A1 : (kb == 2) ? A2 : A3;
#pragma unroll
        for (int nt = 0; nt < 4; ++nt) {
            const int col = nt * 16 + l15;
            const bf16x8 bb = *(const bf16x8*)((const char*)Ys +
                               ((col * 256 + koff) ^ ((col & 7) << 4)));
            acc[nt] = __builtin_amdgcn_mfma_f32_16x16x32_bf16(a, bb, acc[nt], 0, 0, 0);
        }
    }

    __syncthreads();                        // all MFMA LDS reads complete
    unsigned short* Ts = (unsigned short*)smem;
#pragma unroll
    for (int nt = 0; nt < 4; ++nt) {
        const int col = nt * 16 + l15;
#pragma unroll
        for (int r = 0; r < 4; ++r) {
            const int row = 16 * w + hi * 4 + r;
            const float c = sqrtf(fmaxf(x2v[r] + y2c[nt] - 2.f * acc[nt][r], 0.f));
            const _Float16 hv = (_Float16)c;       // RNE
            Ts[row * 67 + col] = *(const unsigned short*)&hv;
        }
    }
    __syncthreads();

    unsigned char* outD = costD + (size_t)bl * (DIAG_N * (size_t)T_);
    const int tbase = gi0 + gj0;
#pragma unroll
    for (int q = 0; q < 16; ++q) {
        const int g = q * 4 + w;                    // 0..63
        const int d = (lane <= g) ? g : g + 64;     // g=63: all lanes -> 63
        const _Float16 hval = *(const _Float16*)&Ts[(d - lane) * 67 + lane];
        const float cf = (float)hval;
        const int pk = __builtin_amdgcn_cvt_pk_fp8_f32(cf, cf, 0, false);
        outD[(size_t)(tbase + d) * T_ + gj0 + lane] = (unsigned char)pk;
    }
}

// ---------------------------------------------------------------------------
// Kernel 2: BIDIRECTIONAL anti-diagonal DTW DP on FP8 costs (R15-proven
// skeleton; fp8 rows are 512 B -> one width-16 global_load_lds covers a PAIR
// of rows; vmcnt counts halved; bwd ring stored memory-ascending, read
// reversed). 2 waves/block: w0 fwd diags 0..511, w1 bwd diags 1022..512;
// in-block combine at the 511/512 cut. ONE dispatch for all 128 batches.
// ---------------------------------------------------------------------------
__global__ __launch_bounds__(128, 1) void dtw_dp_bidi(
    const unsigned char* __restrict__ costD, float* __restrict__ out, int b0)
{
    const int bl  = blockIdx.x;
    const int tid = threadIdx.x;
    const int w   = tid >> 6;
    const int L   = tid & 63;
    // per-lane 16B source offset within each 1024B row-PAIR
    const unsigned char* gbase = costD + (size_t)bl * (DIAG_N * (size_t)T_) + 16 * L;

    __shared__ __align__(16) unsigned char ringF[32][T_];   // 16 KB (wave 0)
    __shared__ __align__(16) unsigned char ringB[32][T_];   // 16 KB (wave 1)
    __shared__ __align__(16) float bb2[T_];                  // B512 handoff
    __shared__ __align__(16) float bb3[T_];                  // B513 handoff

    float va0 = BIGV, va1 = BIGV, va2 = BIGV, va3 = BIGV,
          va4 = BIGV, va5 = BIGV, va6 = BIGV, va7 = BIGV;
    float vb0 = BIGV, vb1 = BIGV, vb2 = BIGV, vb3 = BIGV,
          vb4 = BIGV, vb5 = BIGV, vb6 = BIGV, vb7 = BIGV;
    float s2c;
    uint2 ca0, ca1, ca2, ca3, ca4, ca5, ca6, ca7;   // 8 fp8 costs per tick
    uint2 cb0, cb1, cb2, cb3, cb4, cb5, cb6, cb7;

// load row PAIR (row, row+1) -> ring slots (slot, slot+1); 1024B, width 16
#define GLDP(RING, row, slot)                                               \
    __builtin_amdgcn_global_load_lds(                                       \
        (const __attribute__((address_space(1))) void*)(gbase + (size_t)(row) * T_), \
        (__attribute__((address_space(3))) void*)(&RING[slot][0]), 16, 0, 0)

#define GLD4F(blk) do {                                                     \
    const int r0_ = (blk) * 8, s0_ = ((blk) & 3) * 8;                       \
    GLDP(ringF, r0_ + 0, s0_ + 0); GLDP(ringF, r0_ + 2, s0_ + 2);           \
    GLDP(ringF, r0_ + 4, s0_ + 4); GLDP(ringF, r0_ + 6, s0_ + 6);           \
} while (0)

// bwd block blk consumes rows 1022-8*blk .. 1015-8*blk; store ascending
// (slot q = row 1015-8*blk+q), read reversed in RL8R.
#define GLD4B(blk) do {                                                     \
    const int m0_ = 1015 - (blk) * 8, s0_ = ((blk) & 3) * 8;                \
    GLDP(ringB, m0_ + 0, s0_ + 0); GLDP(ringB, m0_ + 2, s0_ + 2);           \
    GLDP(ringB, m0_ + 4, s0_ + 4); GLDP(ringB, m0_ + 6, s0_ + 6);           \
} while (0)

#define WAITV(n)                                                            \
    do { asm volatile("s_waitcnt vmcnt(" #n ")" ::: "memory");              \
         __builtin_amdgcn_sched_barrier(0); } while (0)

#define SB __builtin_amdgcn_sched_barrier(0)

#define RL8(BK, blk) do {                                                   \
    const unsigned char* rp_ = &ringF[((blk) & 3) * 8][8 * L];              \
    BK##0 = *(const uint2*)(rp_ + 0 * T_);                                  \
    BK##1 = *(const uint2*)(rp_ + 1 * T_);                                  \
    BK##2 = *(const uint2*)(rp_ + 2 * T_);                                  \
    BK##3 = *(const uint2*)(rp_ + 3 * T_);                                  \
    BK##4 = *(const uint2*)(rp_ + 4 * T_);                                  \
    BK##5 = *(const uint2*)(rp_ + 5 * T_);                                  \
    BK##6 = *(const uint2*)(rp_ + 6 * T_);                                  \
    BK##7 = *(const uint2*)(rp_ + 7 * T_);                                  \
} while (0)

#define RL8R(BK, blk) do {                                                  \
    const unsigned char* rp_ = &ringB[((blk) & 3) * 8][8 * L];              \
    BK##0 = *(const uint2*)(rp_ + 7 * T_);                                  \
    BK##1 = *(const uint2*)(rp_ + 6 * T_);                                  \
    BK##2 = *(const uint2*)(rp_ + 5 * T_);                                  \
    BK##3 = *(const uint2*)(rp_ + 4 * T_);                                  \
    BK##4 = *(const uint2*)(rp_ + 3 * T_);                                  \
    BK##5 = *(const uint2*)(rp_ + 2 * T_);                                  \
    BK##6 = *(const uint2*)(rp_ + 1 * T_);                                  \
    BK##7 = *(const uint2*)(rp_ + 0 * T_);                                  \
} while (0)

// unpack 8 fp8 (self-consistent with cost kernel's cvt_pk_fp8_f32 pack)
#define CVT8(Hv)                                                            \
    const f32x2 c01 = __builtin_amdgcn_cvt_pk_f32_fp8((int)Hv.x, false);    \
    const f32x2 c23 = __builtin_amdgcn_cvt_pk_f32_fp8((int)Hv.x, true);     \
    const f32x2 c45 = __builtin_amdgcn_cvt_pk_f32_fp8((int)Hv.y, false);    \
    const f32x2 c67 = __builtin_amdgcn_cvt_pk_f32_fp8((int)Hv.y, true)

#define STEPF_A(Hv) do {                                                    \
    const float s1 = wave_shr1(va7, BIGV);                                  \
    CVT8(Hv);                                                               \
    const float n0 = c01[0] + fminf(fminf(va0, s1),  s2c);                  \
    const float n1 = c01[1] + fminf(fminf(va1, va0), vb0);                  \
    const float n2 = c23[0] + fminf(fminf(va2, va1), vb1);                  \
    const float n3 = c23[1] + fminf(fminf(va3, va2), vb2);                  \
    const float n4 = c45[0] + fminf(fminf(va4, va3), vb3);                  \
    const float n5 = c45[1] + fminf(fminf(va5, va4), vb4);                  \
    const float n6 = c67[0] + fminf(fminf(va6, va5), vb5);                  \
    const float n7 = c67[1] + fminf(fminf(va7, va6), vb6);                  \
    s2c = s1;                                                               \
    vb0 = n0; vb1 = n1; vb2 = n2; vb3 = n3;                                 \
    vb4 = n4; vb5 = n5; vb6 = n6; vb7 = n7;                                 \
} while (0)

#define STEPF_B(Hv) do {                                                    \
    const float s1 = wave_shr1(vb7, BIGV);                                  \
    CVT8(Hv);                                                               \
    const float n0 = c01[0] + fminf(fminf(vb0, s1),  s2c);                  \
    const float n1 = c01[1] + fminf(fminf(vb1, vb0), va0);                  \
    const float n2 = c23[0] + fminf(fminf(vb2, vb1), va1);                  \
    const float n3 = c23[1] + fminf(fminf(vb3, vb2), va2);                  \
    const float n4 = c45[0] + fminf(fminf(vb4, vb3), va3);                  \
    const float n5 = c45[1] + fminf(fminf(vb5, vb4), va4);                  \
    const float n6 = c67[0] + fminf(fminf(vb6, vb5), va5);                  \
    const float n7 = c67[1] + fminf(fminf(vb7, vb6), va6);                  \
    s2c = s1;                                                               \
    va0 = n0; va1 = n1; va2 = n2; va3 = n3;                                 \
    va4 = n4; va5 = n5; va6 = n6; va7 = n7;                                 \
} while (0)

#define STEPB_A(Hv) do {                                                    \
    const float s1 = wave_shl1(va0, BIGV);                                  \
    CVT8(Hv);                                                               \
    const float n7 = c67[1] + fminf(fminf(va7, s1),  s2c);                  \
    const float n6 = c67[0] + fminf(fminf(va6, va7), vb7);                  \
    const float n5 = c45[1] + fminf(fminf(va5, va6), vb6);                  \
    const float n4 = c45[0] + fminf(fminf(va4, va5), vb5);                  \
    const float n3 = c23[1] + fminf(fminf(va3, va4), vb4);                  \
    const float n2 = c23[0] + fminf(fminf(va2, va3), vb3);                  \
    const float n1 = c01[1] + fminf(fminf(va1, va2), vb2);                  \
    const float n0 = c01[0] + fminf(fminf(va0, va1), vb1);                  \
    s2c = s1;                                                               \
    vb0 = n0; vb1 = n1; vb2 = n2; vb3 = n3;                                 \
    vb4 = n4; vb5 = n5; vb6 = n6; vb7 = n7;                                 \
} while (0)

#define STEPB_B(Hv) do {                                                    \
    const float s1 = wave_shl1(vb0, BIGV);                                  \
    CVT8(Hv);                                                               \
    const float n7 = c67[1] + fminf(fminf(vb7, s1),  s2c);                  \
    const float n6 = c67[0] + fminf(fminf(vb6, vb7), va7);                  \
    const float n5 = c45[1] + fminf(fminf(vb5, vb6), va6);                  \
    const float n4 = c45[0] + fminf(fminf(vb4, vb5), va5);                  \
    const float n3 = c23[1] + fminf(fminf(vb3, vb4), va4);                  \
    const float n2 = c23[0] + fminf(fminf(vb2, vb3), va3);                  \
    const float n1 = c01[1] + fminf(fminf(vb1, vb2), va2);                  \
    const float n0 = c01[0] + fminf(fminf(vb0, vb1), va1);                  \
    s2c = s1;                                                               \
    va0 = n0; va1 = n1; va2 = n2; va3 = n3;                                 \
    va4 = n4; va5 = n5; va6 = n6; va7 = n7;                                 \
} while (0)

#define STEPF8(BK)                                                          \
    STEPF_A(BK##0); STEPF_B(BK##1); STEPF_A(BK##2); STEPF_B(BK##3);         \
    STEPF_A(BK##4); STEPF_B(BK##5); STEPF_A(BK##6); STEPF_B(BK##7)
#define STEPB8(BK)                                                          \
    STEPB_A(BK##0); STEPB_B(BK##1); STEPB_A(BK##2); STEPB_B(BK##3);         \
    STEPB_A(BK##4); STEPB_B(BK##5); STEPB_A(BK##6); STEPB_B(BK##7)

    if (w == 0) {
        // ---------------- forward: ticks 0..511 (64 blocks) ----------------
        s2c = (L == 0) ? 0.f : BIGV;       // seeds dp[-1][-1] = 0
        GLD4F(0); GLD4F(1); GLD4F(2); GLD4F(3);      // 16 GLDs outstanding
        WAITV(12); RL8(ca, 0); SB;
        int k = 0;
#pragma unroll 1
        for (int it = 0; it < 30; ++it) {  // blocks 0..59
            WAITV(8); RL8(cb, k + 1); SB; STEPF8(ca); SB; GLD4F(k + 4); SB;
            WAITV(8); RL8(ca, k + 2); SB; STEPF8(cb); SB; GLD4F(k + 5); SB;
            k += 2;
        }
        // k = 60; in flight: blocks 61,62,63 (12 GLDs)
        WAITV(8); RL8(cb, 61); SB; STEPF8(ca); SB;     // block 60
        WAITV(4); RL8(ca, 62); SB; STEPF8(cb); SB;     // block 61
        WAITV(0); RL8(cb, 63); SB; STEPF8(ca); SB;     // block 62
        STEPF8(cb);                                    // block 63 -> tick 511
        // va = F511, vb = F510 (kept live through the barrier)
    } else {
        // ------------- backward: ticks v=0..510 (rows 1022..512) -----------
        s2c = (L == 63) ? 0.f : BIGV;      // seeds B beyond (511,511)
        GLD4B(0); GLD4B(1); GLD4B(2); GLD4B(3);
        WAITV(12); RL8R(ca, 0); SB;
        int k = 0;
#pragma unroll 1
        for (int it = 0; it < 30; ++it) {  // blocks 0..59
            WAITV(8); RL8R(cb, k + 1); SB; STEPB8(ca); SB; GLD4B(k + 4); SB;
            WAITV(8); RL8R(ca, k + 2); SB; STEPB8(cb); SB; GLD4B(k + 5); SB;
            k += 2;
        }
        WAITV(8); RL8R(cb, 61); SB; STEPB8(ca); SB;    // block 60
        WAITV(4); RL8R(ca, 62); SB; STEPB8(cb); SB;    // block 61
        WAITV(0); RL8R(cb, 63); SB; STEPB8(ca); SB;    // block 62
        // block 63 tail: 7 steps (rows 518..512); cb7 (row 511) never stepped
        STEPB_A(cb0); STEPB_B(cb1); STEPB_A(cb2); STEPB_B(cb3);
        STEPB_A(cb4); STEPB_B(cb5); STEPB_A(cb6);      // vb=B512, va=B513
        *(float4*)&bb2[8 * L]     = make_float4(vb0, vb1, vb2, vb3);
        *(float4*)&bb2[8 * L + 4] = make_float4(vb4, vb5, vb6, vb7);
        *(float4*)&bb3[8 * L]     = make_float4(va0, va1, va2, va3);
        *(float4*)&bb3[8 * L + 4] = make_float4(va4, va5, va6, va7);
    }

    __syncthreads();

    if (w == 0) {
        // combine: all path cuts at the diag-511/512 boundary (R11-proven)
        const float4 p0 = *(const float4*)&bb2[8 * L];
        const float4 p1 = *(const float4*)&bb2[8 * L + 4];
        const float4 q0 = *(const float4*)&bb3[8 * L];
        const float4 q1 = *(const float4*)&bb3[8 * L + 4];
        const float b2[8] = {p0.x, p0.y, p0.z, p0.w, p1.x, p1.y, p1.z, p1.w};
        const float b3[8] = {q0.x, q0.y, q0.z, q0.w, q1.x, q1.y, q1.z, q1.w};
        const float F511[8] = {va0, va1, va2, va3, va4, va5, va6, va7};
        const float F510[8] = {vb0, vb1, vb2, vb3, vb4, vb5, vb6, vb7};
        float b2s[8], b3s[8];
#pragma unroll
        for (int kk = 0; kk < 7; ++kk) { b2s[kk] = b2[kk + 1]; b3s[kk] = b3[kk + 1]; }
        b2s[7] = wave_shl1(b2[0], BIGV);   // j+1 across lane boundary
        b3s[7] = wave_shl1(b3[0], BIGV);
        float m = BIGV;
#pragma unroll
        for (int kk = 0; kk < 8; ++kk) {
            const float t1 = F511[kk] + fminf(fminf(b2[kk], b2s[kk]), b3s[kk]);
            const float t2 = F510[kk] + b2s[kk];
            m = fminf(m, fminf(t1, t2));
        }
#pragma unroll
        for (int off = 1; off < 64; off <<= 1)
            m = fminf(m, __shfl_xor(m, off));
        if (L == 0) out[b0 + bl] = m;
    }

#undef GLDP
#undef GLD4F
#undef GLD4B
#undef WAITV
#undef SB
#undef RL8
#undef RL8R
#undef CVT8
#undef STEPF_A
#undef STEPF_B
#undef STEPB_A
#undef STEPB_B
#undef STEPF8
#undef STEPB8
}

// ---------------------------------------------------------------------------
extern "C" void kernel_launch(void* const* d_in, const int* in_sizes, int n_in,
                              void* d_out, int out_size, void* d_ws, size_t ws_size,
                              hipStream_t stream)
{
    const float* x = (const float*)d_in[0];
    const float* y = (const float*)d_in[1];
    float* out = (float*)d_out;

    unsigned short* xt = (unsigned short*)d_ws;
    unsigned short* yt = xt + (size_t)B_ * T_ * F_;
    float* nx = (float*)(yt + (size_t)B_ * T_ * F_);
    float* ny = nx + (size_t)B_ * T_;
    unsigned char* costD = (unsigned char*)(ny + (size_t)B_ * T_);
    const size_t head = (size_t)(costD - (unsigned char*)d_ws);

    // fp8 diag cost: 0.5 MiB per batch -> 128 batches need head + 64 MiB
    const size_t perb = (size_t)DIAG_N * T_;   // bytes
    int Bg = 8;
    for (int g = 128; g >= 8; g >>= 1)
        if (ws_size >= head + perb * (size_t)g) { Bg = g; break; }

    hipLaunchKernelGGL(dtw_prep_kernel, dim3(T_ / 64, B_, 2), dim3(256), 0, stream,
                       x, y, xt, yt, nx, ny);

    for (int b0 = 0; b0 < B_; b0 += Bg) {
        dim3 gc(T_ / TS, T_ / TS, Bg);
        hipLaunchKernelGGL(dtw_cost_kernel, gc, dim3(256), 0, stream,
                           xt, yt, nx, ny, costD, b0);
        hipLaunchKernelGGL(dtw_dp_bidi, dim3(Bg), dim3(128), 0, stream,
                           costD, out, b0);
    }
}